// Round 11
// baseline (256.286 us; speedup 1.0000x reference)
//
#include <hip/hip_runtime.h>

// Problem constants (fixed by the reference).
constexpr int N = 100000;   // nodes
constexpr int E = 1600000;  // edges
constexpr int D = 128;      // feature dim (both layers)
constexpr int M = 5000;     // mask size

constexpr int MF_BLKS = (N + 255) / 256;           // 391 mfma-gemm blocks (256 rows each)

// Counting-sort CSR build parameters.
// Bucket = dst>>7 (128 nodes) -> 782 buckets, each with a FIXED 3072-record slot in
// tmp/pairs: counts are Binomial(1.6M, 1/782) = 2046 +/- 45, CAP is +22 sigma.
// No histogram, no scan; cursors are RELATIVE (start 0, zeroed by the memset), so
// no cursor-init kernel either (R11).
// R8 lesson: per-dst global float atomics (1.6M random lines) cost ~70us -- dis is
// computed by streaming bucket slots with LDS accumulation (k_disA_g1).
// R10 lesson: gather-loop depth tiers beyond 8 add VALU cost, no win (reverted).
// R11: 5 launches total -- W1-prep/maskbit ride in k_part; needed-scan rides in
// k_disA_g1 (boundaries cost ~10us each, R7->R9 measurement).
constexpr int NBITS = 7;
constexpr int BUCKET = 1 << NBITS;                 // 128 nodes per bucket
constexpr int NB  = (N + BUCKET - 1) / BUCKET;     // 782 buckets
constexpr int CAP = 3072;                          // records per bucket slot (= 512*6)
constexpr int EBP = 4096;                          // edges per partition block
constexpr int NPP = (E + EBP - 1) / EBP;           // 391 partition blocks (1024 thr each)
constexpr int PREP_BLKS = 8;                       // W1-prep ride-along blocks (1024 thr)
constexpr int MB_BLKS = (M + 1023) / 1024;         // 5 maskbit ride-along blocks
constexpr int SCAN_BLKS = (E + 4095) / 4096;       // 391 needed-scan blocks (256 thr x 16)

typedef __attribute__((ext_vector_type(8))) short bf16x8;
typedef __attribute__((ext_vector_type(4))) float f32x4;

// ---------------- bf16 helpers (RNE pack, cheap unpack) ----------------

__device__ __forceinline__ unsigned int pack_bf16x2(float a, float b) {
    unsigned int ua = __float_as_uint(a);
    unsigned int ub = __float_as_uint(b);
    ua = (ua + 0x7FFFu + ((ua >> 16) & 1u)) >> 16;
    ub = (ub + 0x7FFFu + ((ub >> 16) & 1u)) & 0xFFFF0000u;
    return ua | ub;
}
__device__ __forceinline__ unsigned short bf16_rne(float a) {
    unsigned int ua = __float_as_uint(a);
    return (unsigned short)((ua + 0x7FFFu + ((ua >> 16) & 1u)) >> 16);
}
__device__ __forceinline__ float bf16_lo(unsigned int u) { return __uint_as_float(u << 16); }
__device__ __forceinline__ float bf16_hi(unsigned int u) { return __uint_as_float(u & 0xFFFF0000u); }

// ---------------- partition (+ W1-prep, maskbit ride-alongs) ----------------
// record: bits[6:0]=d&127, bits[26:7]=src, bits[63:32]=ew bits.
// Cursors are bucket-relative (zeroed by memset); pos = b*CAP + off+r.
// Ride-alongs: W1 bf16-transpose prep (Wt1 consumed next kernel) and maskbit/needed
// seeding from mask[] (maskbit consumed next kernel). The partition path itself has
// NO per-edge bitmap work (moved to k_disA_g1's scan blocks).

__global__ __launch_bounds__(1024) void k_part(const int* __restrict__ src,
                                               const int* __restrict__ dst,
                                               const float* __restrict__ ew,
                                               int* __restrict__ gCursor,
                                               unsigned long long* __restrict__ tmp,
                                               const float* __restrict__ W1,
                                               unsigned int* __restrict__ Wt1,
                                               const int* __restrict__ mask,
                                               unsigned int* __restrict__ maskbit,
                                               unsigned int* __restrict__ needed) {
    __shared__ int cnt[NB];
    __shared__ int off[NB];
    __shared__ int rk[NB];
    const int t = threadIdx.x;

    if (blockIdx.x >= NPP) {
        const int bi = blockIdx.x - NPP;
        if (bi < PREP_BLKS) {
            int idx = bi * 1024 + t;   // 8192 total (W1 only; W2 used in fp32)
            if (idx < 8192) {
                int n = idx >> 6, kk = idx & 63;
                float a = W1[(2 * kk) * D + n];
                float b = W1[(2 * kk + 1) * D + n];
                Wt1[idx] = pack_bf16x2(a, b);
            }
        } else {
            int i = (bi - PREP_BLKS) * 1024 + t;
            if (i < M) {
                int n = mask[i];
                atomicOr(&maskbit[n >> 5], 1u << (n & 31));
                atomicOr(&needed[n >> 5], 1u << (n & 31));  // masked nodes need their row
            }
        }
        return;
    }

    for (int i = t; i < NB; i += 1024) { cnt[i] = 0; rk[i] = 0; }
    __syncthreads();

    const int eb = blockIdx.x * EBP;
    int d_[4], s_[4];
    float w_[4];
#pragma unroll
    for (int i = 0; i < 4; ++i) {
        int e = eb + t + i * 1024;
        if (e < E) {
            d_[i] = __builtin_nontemporal_load(dst + e);
            s_[i] = __builtin_nontemporal_load(src + e);
            w_[i] = __builtin_nontemporal_load(ew + e);
            atomicAdd(&cnt[d_[i] >> NBITS], 1);
        } else {
            d_[i] = -1;
        }
    }
    __syncthreads();

    for (int i = t; i < NB; i += 1024) {
        int c = cnt[i];
        if (c > 0) off[i] = atomicAdd(&gCursor[i], c);   // relative reservation
    }
    __syncthreads();

#pragma unroll
    for (int i = 0; i < 4; ++i) {
        if (d_[i] >= 0) {
            int b = d_[i] >> NBITS;
            int r = atomicAdd(&rk[b], 1);
            int posr = off[b] + r;
            if (posr < CAP) {   // overflow guard (+22 sigma; never expected)
                unsigned long long rec =
                    ((unsigned long long)(unsigned int)__float_as_int(w_[i]) << 32) |
                    ((unsigned int)s_[i] << NBITS) | (unsigned int)(d_[i] & (BUCKET - 1));
                tmp[(size_t)b * CAP + posr] = rec;   // cached: L2 merges the ~42B runs
            }
        }
    }
}

// ---------------- shared-memory union: GEMM W-tile OR dis-accumulation array ----------------

union SMem {
    unsigned int Ws[128 * 68];
    float wsumL[BUCKET];
};

// ---------------- MFMA GEMM body: 256 rows/block, 4 waves; wave = 64 rows x 128 cols ----------------
// A-frag: A[m=lane&15][k=quad*8+j]; B-frag: B[k=quad*8+j][n=lane&15];
// D: col=lane&15, row=quad*4+reg  (HW-verified layouts, 16x16x32 bf16).
// W^T staged in LDS with 68-uint row stride (bank-conflict padding).

__device__ __forceinline__ void gemm_mfma_body(unsigned int* __restrict__ Ws,
                                               const float* __restrict__ Xin,
                                               const unsigned int* __restrict__ Wt,
                                               unsigned short* __restrict__ out, int blk) {
    const int t = threadIdx.x;
#pragma unroll
    for (int i = 0; i < 8; ++i) {
        int f4 = t + i * 256;        // uint4 index, 2048 total
        int n = f4 >> 4;
        int k4 = f4 & 15;
        uint4 w = ((const uint4*)Wt)[f4];
        *(uint4*)(&Ws[n * 68 + k4 * 4]) = w;
    }
    __syncthreads();

    const int wv = t >> 6, lane = t & 63;
    const int q = lane >> 4, l15 = lane & 15;
    const int rowBase = blk * 256 + wv * 64;

    f32x4 acc[4][8] = {};
#pragma unroll
    for (int kc = 0; kc < 4; ++kc) {
        bf16x8 af[4];
#pragma unroll
        for (int rt = 0; rt < 4; ++rt) {
            int row = rowBase + rt * 16 + l15;
            if (row > N - 1) row = N - 1;   // tail: duplicate last row, stores guarded
            union { uint4 u; bf16x8 v; } cv;
            const float* xr = Xin + (size_t)row * D + kc * 32 + q * 8;
            float4 x0 = *(const float4*)xr;
            float4 x1 = *(const float4*)(xr + 4);
            cv.u.x = pack_bf16x2(x0.x, x0.y);
            cv.u.y = pack_bf16x2(x0.z, x0.w);
            cv.u.z = pack_bf16x2(x1.x, x1.y);
            cv.u.w = pack_bf16x2(x1.z, x1.w);
            af[rt] = cv.v;
        }
#pragma unroll
        for (int ct = 0; ct < 8; ++ct) {
            union { uint4 u; bf16x8 v; } bv;
            bv.u = *(const uint4*)(&Ws[(ct * 16 + l15) * 68 + kc * 16 + q * 4]);
#pragma unroll
            for (int rt = 0; rt < 4; ++rt)
                acc[rt][ct] = __builtin_amdgcn_mfma_f32_16x16x32_bf16(af[rt], bv.v, acc[rt][ct], 0, 0, 0);
        }
    }

#pragma unroll
    for (int rt = 0; rt < 4; ++rt) {
#pragma unroll
        for (int ct = 0; ct < 8; ++ct) {
            int col = ct * 16 + l15;
#pragma unroll
            for (int r = 0; r < 4; ++r) {
                int row = rowBase + rt * 16 + q * 4 + r;
                if (row < N) out[(size_t)row * D + col] = bf16_rne(acc[rt][ct][r]);
            }
        }
    }
}

// ---------------- fused: GEMM1 + per-bucket dis + needed-set scan ----------------
// [0, MF_BLKS): A = x@W1 (long pole, dispatched first).
// [MF_BLKS, MF_BLKS+NB): stream bucket slot, LDS-accumulate wsum, dis=rsqrt(1+wsum).
// [then SCAN_BLKS): per-edge maskbit lookup -> needed bitmap (consumed by k_sort_agg).

__global__ __launch_bounds__(256) void k_disA_g1(const unsigned long long* __restrict__ tmp,
                                                 const int* __restrict__ gCursor,
                                                 float* __restrict__ dis,
                                                 const float* __restrict__ x,
                                                 const unsigned int* __restrict__ Wt1,
                                                 unsigned short* __restrict__ A,
                                                 const int* __restrict__ src,
                                                 const int* __restrict__ dst,
                                                 const unsigned int* __restrict__ maskbit,
                                                 unsigned int* __restrict__ needed) {
    __shared__ SMem sm;
    const int t = threadIdx.x;
    if (blockIdx.x < MF_BLKS) {
        gemm_mfma_body(sm.Ws, x, Wt1, A, blockIdx.x);
    } else if (blockIdx.x < MF_BLKS + NB) {
        const int bk = blockIdx.x - MF_BLKS;
        if (t < BUCKET) sm.wsumL[t] = 0.f;
        __syncthreads();
        const size_t segBeg = (size_t)bk * CAP;
        int segLen = gCursor[bk];
        if (segLen > CAP) segLen = CAP;
        for (int e = t; e < segLen; e += 256) {
            unsigned long long rec = tmp[segBeg + e];
            atomicAdd(&sm.wsumL[(int)(rec & (BUCKET - 1))],
                      __uint_as_float((unsigned int)(rec >> 32)));
        }
        __syncthreads();
        if (t < BUCKET) {
            int node = bk * BUCKET + t;
            if (node < N) dis[node] = rsqrtf(1.0f + sm.wsumL[t]);
        }
    } else {
        const int base = (blockIdx.x - MF_BLKS - NB) * 4096;
#pragma unroll
        for (int i = 0; i < 16; ++i) {
            int e = base + t + i * 256;
            if (e < E) {
                int d = __builtin_nontemporal_load(dst + e);
                if ((maskbit[d >> 5] >> (d & 31)) & 1u) {
                    int s = src[e];
                    atomicOr(&needed[s >> 5], 1u << (s & 31));
                }
            }
        }
    }
}

// ---------------- fused sort+aggregate: block (512 thr) per bucket ----------------
// Records live in REGISTERS (<=6/thread since CAP = 512*6): phase0 counts via LDS
// atomics; prefix -> offL, rowStart/rowLen, needed worklist; phase1 scatters
// (src, ew*dis[src]) into LDS (global pairs only for masked dsts); phase2: waves
// pop needed nodes from the worklist and gather-aggregate (8-deep + scalar tail --
// R10 showed deeper tiering costs VALU with no gain).

__global__ __launch_bounds__(512) void k_sort_agg(const unsigned long long* __restrict__ tmp,
                                                  const int* __restrict__ gCursor,
                                                  const float* __restrict__ dis,
                                                  const unsigned int* __restrict__ needed,
                                                  const unsigned int* __restrict__ maskbit,
                                                  const float* __restrict__ b,
                                                  const unsigned int* __restrict__ Hb,
                                                  int* __restrict__ rowStart,
                                                  int* __restrict__ rowLen,
                                                  int2* __restrict__ pairs,
                                                  unsigned int* __restrict__ outB) {
    __shared__ int2 lp[CAP];
    __shared__ int cnt[BUCKET];
    __shared__ int offL[BUCKET + 1];
    __shared__ int wl[BUCKET];
    __shared__ int waveS[2];
    __shared__ int nw, wcur;
    const int bk = blockIdx.x;
    const int t = threadIdx.x;
    const size_t segBeg = (size_t)bk * CAP;
    int segLen = gCursor[bk];
    if (segLen > CAP) segLen = CAP;   // matches k_part's overflow guard

    if (t == 0) { nw = 0; wcur = 0; offL[BUCKET] = segLen; }
    if (t < BUCKET) cnt[t] = 0;
    const uint4 mb4 = ((const uint4*)maskbit)[bk];   // this bucket's 128 mask bits
    __syncthreads();

    // phase 0: load records into registers, count per local-dst
    unsigned long long r_[6];
#pragma unroll
    for (int i = 0; i < 6; ++i) {
        int e = t + i * 512;
        if (e < segLen) {
            r_[i] = tmp[segBeg + e];
            atomicAdd(&cnt[(int)(r_[i] & (BUCKET - 1))], 1);
        }
    }
    __syncthreads();

    // prefix over cnt (threads 0..127), rowStart/rowLen, worklist build
    const int lane = t & 63;
    {
        const int wv2 = t >> 6;
        const int pv = (t < BUCKET) ? cnt[t] : 0;
        int v = pv;
        for (int o = 1; o < 64; o <<= 1) {
            int u = __shfl_up(v, o);
            if (lane >= o) v += u;
        }
        if (lane == 63 && wv2 < 2) waveS[wv2] = v;
        __syncthreads();
        if (t < BUCKET) {
            const int wb = (wv2 == 1) ? waveS[0] : 0;
            const int ex = wb + v - pv;
            offL[t] = ex;
            const int node = bk * BUCKET + t;
            if (node < N) {
                rowStart[node] = (int)segBeg + ex;
                rowLen[node] = pv;
                if ((needed[node >> 5] >> (node & 31)) & 1u) {
                    int r = atomicAdd(&nw, 1);
                    wl[r] = t;
                }
            }
            cnt[t] = 0;
        }
    }
    __syncthreads();

    // phase 1: scatter registers -> LDS (prescaled); global pairs only for masked dsts
#pragma unroll
    for (int i = 0; i < 6; ++i) {
        int e = t + i * 512;
        if (e < segLen) {
            unsigned long long rec = r_[i];
            int dl = (int)(rec & (BUCKET - 1));
            int s  = (int)((rec >> NBITS) & 0xFFFFF);
            float w = __uint_as_float((unsigned int)(rec >> 32));
            float v = w * dis[s];             // per-thread gather, 64 edges/instr
            int r = atomicAdd(&cnt[dl], 1);
            int pos = offL[dl] + r;
            int2 pr = make_int2(s, __float_as_int(v));
            lp[pos] = pr;
            unsigned int mw = (dl < 32) ? mb4.x : (dl < 64) ? mb4.y : (dl < 96) ? mb4.z : mb4.w;
            if ((mw >> (dl & 31)) & 1u) pairs[segBeg + pos] = pr;
        }
    }
    __syncthreads();

    // phase 2: waves pop needed nodes from the worklist
    for (;;) {
        int idx;
        if (lane == 0) idx = atomicAdd(&wcur, 1);
        idx = __shfl(idx, 0);
        if (idx >= nw) break;
        const int nl = wl[idx];
        const int node = bk * BUCKET + nl;
        const int beg = offL[nl], end = offL[nl + 1];
        float ax = 0.f, ay = 0.f;
        int j = beg;
        for (; j + 7 < end; j += 8) {
            int2 p[8];
            unsigned int h[8];
#pragma unroll
            for (int i = 0; i < 8; ++i) p[i] = lp[j + i];
#pragma unroll
            for (int i = 0; i < 8; ++i) h[i] = Hb[(size_t)p[i].x * 64 + lane];
#pragma unroll
            for (int i = 0; i < 8; ++i) {
                float v = __int_as_float(p[i].y);
                ax += bf16_lo(h[i]) * v;
                ay += bf16_hi(h[i]) * v;
            }
        }
        for (; j < end; ++j) {
            int2 p0 = lp[j];
            unsigned int h0 = Hb[(size_t)p0.x * 64 + lane];
            float v0 = __int_as_float(p0.y);
            ax += bf16_lo(h0) * v0;
            ay += bf16_hi(h0) * v0;
        }
        float dd = dis[node];
        float sn = dd * dd;  // self-loop norm = 1/deg
        unsigned int hs = Hb[(size_t)node * 64 + lane];
        float2 bb = ((const float2*)b)[lane];
        float ox = fmaxf(ax * dd + bf16_lo(hs) * sn + bb.x, 0.f);
        float oy = fmaxf(ay * dd + bf16_hi(hs) * sn + bb.y, 0.f);
        __builtin_nontemporal_store(pack_bf16x2(ox, oy), outB + (size_t)node * 64 + lane);
    }
}

// ---------------- fused layer-2 at mask nodes: out = agg(B)@W2 + b2 ----------------
// (agg is linear, so agg(B@W2) = agg(B)@W2.) Wave per mask row: gather-aggregate B,
// park the row in LDS, then multiply by W2 staged in LDS (two 64-row halves).

__global__ __launch_bounds__(256) void k_mask_out(const unsigned int* __restrict__ Hb,
                                                  const int2* __restrict__ pairs,
                                                  const int* __restrict__ rowStart,
                                                  const int* __restrict__ rowLen,
                                                  const float* __restrict__ dis,
                                                  const float* __restrict__ W2,
                                                  const float* __restrict__ b2,
                                                  const int* __restrict__ mask,
                                                  const int* __restrict__ y,
                                                  float* __restrict__ out) {
    __shared__ float w2s[64 * 132];   // 132 stride: float4-aligned stores, bank spread
    __shared__ float rowL[4][128];
    const int t = threadIdx.x;
    const int wv = t >> 6, lane = t & 63;
    const int i = blockIdx.x * 4 + wv;   // grid = M/4 exactly (1250*4 = 5000)
    const int node = mask[i];
    const int beg = rowStart[node], end = beg + rowLen[node];

    float ax = 0.f, ay = 0.f;
    int j = beg;
    for (; j + 7 < end; j += 8) {
        int2 p[8];
        unsigned int h[8];
#pragma unroll
        for (int ii = 0; ii < 8; ++ii) p[ii] = pairs[j + ii];
#pragma unroll
        for (int ii = 0; ii < 8; ++ii) h[ii] = Hb[(size_t)p[ii].x * 64 + lane];
#pragma unroll
        for (int ii = 0; ii < 8; ++ii) {
            float v = __int_as_float(p[ii].y);
            ax += bf16_lo(h[ii]) * v;
            ay += bf16_hi(h[ii]) * v;
        }
    }
    for (; j < end; ++j) {
        int2 p0 = pairs[j];
        unsigned int h0 = Hb[(size_t)p0.x * 64 + lane];
        float v0 = __int_as_float(p0.y);
        ax += bf16_lo(h0) * v0;
        ay += bf16_hi(h0) * v0;
    }
    {
        float dd = dis[node];
        float sn = dd * dd;
        unsigned int hs = Hb[(size_t)node * 64 + lane];
        rowL[wv][2 * lane]     = ax * dd + bf16_lo(hs) * sn;   // bias b2 added post-GEMM
        rowL[wv][2 * lane + 1] = ay * dd + bf16_hi(hs) * sn;
    }

    float2 bb = ((const float2*)b2)[lane];
    float acc0 = bb.x, acc1 = bb.y;
#pragma unroll
    for (int h0 = 0; h0 < 2; ++h0) {
        __syncthreads();
        for (int idx = t; idx < 2048; idx += 256) {   // stage 64 rows of W2 (float4 units)
            float4 v = ((const float4*)W2)[h0 * 2048 + idx];
            int k = (idx * 4) >> 7, n = (idx * 4) & 127;
            *(float4*)(&w2s[k * 132 + n]) = v;
        }
        __syncthreads();
#pragma unroll 8
        for (int k = 0; k < 64; ++k) {
            float a = rowL[wv][h0 * 64 + k];
            float2 w = *(const float2*)(&w2s[k * 132 + 2 * lane]);
            acc0 += a * w.x;
            acc1 += a * w.y;
        }
    }
    ((float2*)(out + (size_t)i * D))[lane] = make_float2(acc0, acc1);
    if (lane == 0) out[(size_t)M * D + i] = (float)y[node];
}

extern "C" void kernel_launch(void* const* d_in, const int* in_sizes, int n_in,
                              void* d_out, int out_size, void* d_ws, size_t ws_size,
                              hipStream_t stream) {
    const float* x  = (const float*)d_in[0];
    const float* ew = (const float*)d_in[1];
    const float* W1 = (const float*)d_in[2];
    const float* b1 = (const float*)d_in[3];
    const float* W2 = (const float*)d_in[4];
    const float* b2 = (const float*)d_in[5];
    const int* eidx = (const int*)d_in[6];
    const int* mask = (const int*)d_in[7];
    const int* y    = (const int*)d_in[8];
    const int* src = eidx;       // edge_index[0]
    const int* dst = eidx + E;   // edge_index[1]

    // Workspace layout (bytes):
    //   dis       @ 0        : N f32        (0.4 MB)
    //   rowStart  @ 512 KB   : N i32        (0.4 MB)
    //   rowLen    @ 1024 KB  : N i32        (0.4 MB)
    //   maskbit   @ 1440 KB  : 16 KB bitmap }
    //   needed    @ 1456 KB  : 16 KB bitmap }  zeroed together (36 KB memset,
    //   gCursor   @ 1472 KB  : NB i32       }   covers relative cursors too)
    //   Wt1       @ 1480 KB  : 8192 u32    (32 KB)
    //   pairs     @ 2 MB     : NB*CAP int2 (19.2 MB, sparsely written)
    //   tmp       @ 22 MB    : NB*CAP u64  (19.2 MB)
    //   A  (bf16) @ 42 MB    : N*D bf16    (25.6 MB)
    //   B  (bf16) @ 68 MB    : N*D bf16    (25.6 MB)   total ~94 MB
    char* ws = (char*)d_ws;
    float* dis      = (float*)(ws);
    int*   rowStart = (int*)(ws + (size_t)512 * 1024);
    int*   rowLen   = (int*)(ws + (size_t)1024 * 1024);
    unsigned int* maskbit = (unsigned int*)(ws + (size_t)1440 * 1024);
    unsigned int* needed  = (unsigned int*)(ws + (size_t)1456 * 1024);
    int*   gCursor  = (int*)(ws + (size_t)1472 * 1024);
    unsigned int* Wt1 = (unsigned int*)(ws + (size_t)1480 * 1024);
    int2*  pairs    = (int2*)(ws + (size_t)2 * 1024 * 1024);
    unsigned long long* tmp = (unsigned long long*)(ws + (size_t)22 * 1024 * 1024);
    unsigned short* A  = (unsigned short*)(ws + (size_t)42 * 1024 * 1024);
    unsigned short* B  = (unsigned short*)(ws + (size_t)68 * 1024 * 1024);

    // --- zero bitmaps + relative cursors ---
    (void)hipMemsetAsync(ws + (size_t)1440 * 1024, 0, (size_t)36 * 1024, stream);

    // --- partition via atomic run reservation (+ W1 prep, maskbit ride-alongs) ---
    hipLaunchKernelGGL(k_part, dim3(NPP + PREP_BLKS + MB_BLKS), dim3(1024), 0, stream,
                       src, dst, ew, gCursor, tmp, W1, Wt1, mask, maskbit, needed);

    // --- GEMM1 + per-bucket dis + needed-set scan (one launch) ---
    hipLaunchKernelGGL(k_disA_g1, dim3(MF_BLKS + NB + SCAN_BLKS), dim3(256), 0, stream,
                       tmp, gCursor, dis, x, Wt1, A, src, dst, maskbit, needed);

    // --- fused sort + layer-1 aggregate: B = relu(agg(A) + b1); pairs for masked dsts ---
    hipLaunchKernelGGL(k_sort_agg, dim3(NB), dim3(512), 0, stream,
                       tmp, gCursor, dis, needed, maskbit, b1,
                       (const unsigned int*)A, rowStart, rowLen, pairs, (unsigned int*)B);

    // --- fused layer-2 at mask nodes: out = agg(B)@W2 + b2 (+ labels) ---
    hipLaunchKernelGGL(k_mask_out, dim3(M / 4), dim3(256), 0, stream,
                       (const unsigned int*)B, pairs, rowStart, rowLen, dis, W2, b2,
                       mask, y, (float*)d_out);
}

// Round 12
// 238.694 us; speedup vs baseline: 1.0737x; 1.0737x over previous
//
#include <hip/hip_runtime.h>

// Problem constants (fixed by the reference).
constexpr int N = 100000;   // nodes
constexpr int E = 1600000;  // edges
constexpr int D = 128;      // feature dim (both layers)
constexpr int M = 5000;     // mask size

constexpr int MF_BLKS = (N + 255) / 256;           // 391 mfma-gemm blocks (256 rows each)

// Counting-sort CSR build parameters.
// Bucket = dst>>7 (128 nodes) -> 782 buckets, each with a FIXED 3072-record slot in
// tmp/pairs: counts are Binomial(1.6M, 1/782) = 2046 +/- 45, CAP is +22 sigma.
// No histogram, no scan; cursors are RELATIVE (start 0, zeroed by the memset).
// R8 lesson: per-dst global float atomics (1.6M random lines) cost ~70us.
// R10 lesson: gather tiers beyond 8-deep add VALU cost, no win.
// R11 lesson: the needed-scan must live in k_part (high TLP, operands in registers);
// moving it into the VGPR-140 GEMM kernel starved it at 3 blocks/CU (+20us).
// Hence maskbit is seeded in k_misc0 (the launch before k_part).
constexpr int NBITS = 7;
constexpr int BUCKET = 1 << NBITS;                 // 128 nodes per bucket
constexpr int NB  = (N + BUCKET - 1) / BUCKET;     // 782 buckets
constexpr int CAP = 3072;                          // records per bucket slot (= 512*6)
constexpr int EBP = 4096;                          // edges per partition block
constexpr int NPP = (E + EBP - 1) / EBP;           // 391 partition blocks (1024 thr each)
constexpr int PREP_BLKS = 32;                      // weight-prep blocks (W1 only, 256 thr)
constexpr int MB_BLKS = (M + 255) / 256;           // 20 maskbit blocks

typedef __attribute__((ext_vector_type(8))) short bf16x8;
typedef __attribute__((ext_vector_type(4))) float f32x4;

// ---------------- bf16 helpers (RNE pack, cheap unpack) ----------------

__device__ __forceinline__ unsigned int pack_bf16x2(float a, float b) {
    unsigned int ua = __float_as_uint(a);
    unsigned int ub = __float_as_uint(b);
    ua = (ua + 0x7FFFu + ((ua >> 16) & 1u)) >> 16;
    ub = (ub + 0x7FFFu + ((ub >> 16) & 1u)) & 0xFFFF0000u;
    return ua | ub;
}
__device__ __forceinline__ unsigned short bf16_rne(float a) {
    unsigned int ua = __float_as_uint(a);
    return (unsigned short)((ua + 0x7FFFu + ((ua >> 16) & 1u)) >> 16);
}
__device__ __forceinline__ float bf16_lo(unsigned int u) { return __uint_as_float(u << 16); }
__device__ __forceinline__ float bf16_hi(unsigned int u) { return __uint_as_float(u & 0xFFFF0000u); }

// ---------------- misc0: W1 prep + maskbit/needed seed (no cursor init: memset) ----------------

__global__ __launch_bounds__(256) void k_misc0(const float* __restrict__ W1,
                                               unsigned int* __restrict__ Wt1,
                                               const int* __restrict__ mask,
                                               unsigned int* __restrict__ maskbit,
                                               unsigned int* __restrict__ needed) {
    const int t = threadIdx.x;
    if (blockIdx.x < PREP_BLKS) {
        int idx = blockIdx.x * 256 + t;   // 8192 total (W1 only; W2 used in fp32)
        int n = idx >> 6, kk = idx & 63;
        float a = W1[(2 * kk) * D + n];
        float b = W1[(2 * kk + 1) * D + n];
        Wt1[idx] = pack_bf16x2(a, b);
    } else {
        int i = (blockIdx.x - PREP_BLKS) * 256 + t;
        if (i < M) {
            int n = mask[i];
            atomicOr(&maskbit[n >> 5], 1u << (n & 31));
            atomicOr(&needed[n >> 5], 1u << (n & 31));  // masked nodes need their own row
        }
    }
}

// ---------------- partition: register-stash + atomic run reservation ----------------
// record: bits[6:0]=d&127, bits[26:7]=src, bits[63:32]=ew bits.
// Cursors bucket-relative (zeroed by memset); pos = b*CAP + off+r.
// Fused needed-set scan (src/dst in registers; maskbit is an L1-resident 16KB table,
// seeded by k_misc0 in the PREVIOUS launch -- no intra-kernel race).
// 391 blocks x 16 waves (R10 occupancy fix); 4 records/thread.

__global__ __launch_bounds__(1024) void k_part(const int* __restrict__ src,
                                               const int* __restrict__ dst,
                                               const float* __restrict__ ew,
                                               int* __restrict__ gCursor,
                                               unsigned long long* __restrict__ tmp,
                                               const unsigned int* __restrict__ maskbit,
                                               unsigned int* __restrict__ needed) {
    __shared__ int cnt[NB];
    __shared__ int off[NB];
    __shared__ int rk[NB];
    const int t = threadIdx.x;
    for (int i = t; i < NB; i += 1024) { cnt[i] = 0; rk[i] = 0; }
    __syncthreads();

    const int eb = blockIdx.x * EBP;
    int d_[4], s_[4];
    float w_[4];
#pragma unroll
    for (int i = 0; i < 4; ++i) {
        int e = eb + t + i * 1024;
        if (e < E) {
            d_[i] = __builtin_nontemporal_load(dst + e);
            s_[i] = __builtin_nontemporal_load(src + e);
            w_[i] = __builtin_nontemporal_load(ew + e);
            atomicAdd(&cnt[d_[i] >> NBITS], 1);
        } else {
            d_[i] = -1;
        }
    }
    __syncthreads();

    for (int i = t; i < NB; i += 1024) {
        int c = cnt[i];
        if (c > 0) off[i] = atomicAdd(&gCursor[i], c);   // relative reservation
    }
    __syncthreads();

#pragma unroll
    for (int i = 0; i < 4; ++i) {
        if (d_[i] >= 0) {
            int b = d_[i] >> NBITS;
            int r = atomicAdd(&rk[b], 1);
            int posr = off[b] + r;
            if (posr < CAP) {   // overflow guard (+22 sigma; never expected)
                unsigned long long rec =
                    ((unsigned long long)(unsigned int)__float_as_int(w_[i]) << 32) |
                    ((unsigned int)s_[i] << NBITS) | (unsigned int)(d_[i] & (BUCKET - 1));
                tmp[(size_t)b * CAP + posr] = rec;   // cached: L2 merges the ~42B runs
            }
            if ((maskbit[d_[i] >> 5] >> (d_[i] & 31)) & 1u)
                atomicOr(&needed[s_[i] >> 5], 1u << (s_[i] & 31));
        }
    }
}

// ---------------- shared-memory union: GEMM W-tile OR dis-accumulation array ----------------

union SMem {
    unsigned int Ws[128 * 68];
    float wsumL[BUCKET];
};

// ---------------- MFMA GEMM body: 256 rows/block, 4 waves; wave = 64 rows x 128 cols ----------------
// A-frag: A[m=lane&15][k=quad*8+j]; B-frag: B[k=quad*8+j][n=lane&15];
// D: col=lane&15, row=quad*4+reg  (HW-verified layouts, 16x16x32 bf16).
// W^T staged in LDS with 68-uint row stride (bank-conflict padding).

__device__ __forceinline__ void gemm_mfma_body(unsigned int* __restrict__ Ws,
                                               const float* __restrict__ Xin,
                                               const unsigned int* __restrict__ Wt,
                                               unsigned short* __restrict__ out, int blk) {
    const int t = threadIdx.x;
#pragma unroll
    for (int i = 0; i < 8; ++i) {
        int f4 = t + i * 256;        // uint4 index, 2048 total
        int n = f4 >> 4;
        int k4 = f4 & 15;
        uint4 w = ((const uint4*)Wt)[f4];
        *(uint4*)(&Ws[n * 68 + k4 * 4]) = w;
    }
    __syncthreads();

    const int wv = t >> 6, lane = t & 63;
    const int q = lane >> 4, l15 = lane & 15;
    const int rowBase = blk * 256 + wv * 64;

    f32x4 acc[4][8] = {};
#pragma unroll
    for (int kc = 0; kc < 4; ++kc) {
        bf16x8 af[4];
#pragma unroll
        for (int rt = 0; rt < 4; ++rt) {
            int row = rowBase + rt * 16 + l15;
            if (row > N - 1) row = N - 1;   // tail: duplicate last row, stores guarded
            union { uint4 u; bf16x8 v; } cv;
            const float* xr = Xin + (size_t)row * D + kc * 32 + q * 8;
            float4 x0 = *(const float4*)xr;
            float4 x1 = *(const float4*)(xr + 4);
            cv.u.x = pack_bf16x2(x0.x, x0.y);
            cv.u.y = pack_bf16x2(x0.z, x0.w);
            cv.u.z = pack_bf16x2(x1.x, x1.y);
            cv.u.w = pack_bf16x2(x1.z, x1.w);
            af[rt] = cv.v;
        }
#pragma unroll
        for (int ct = 0; ct < 8; ++ct) {
            union { uint4 u; bf16x8 v; } bv;
            bv.u = *(const uint4*)(&Ws[(ct * 16 + l15) * 68 + kc * 16 + q * 4]);
#pragma unroll
            for (int rt = 0; rt < 4; ++rt)
                acc[rt][ct] = __builtin_amdgcn_mfma_f32_16x16x32_bf16(af[rt], bv.v, acc[rt][ct], 0, 0, 0);
        }
    }

#pragma unroll
    for (int rt = 0; rt < 4; ++rt) {
#pragma unroll
        for (int ct = 0; ct < 8; ++ct) {
            int col = ct * 16 + l15;
#pragma unroll
            for (int r = 0; r < 4; ++r) {
                int row = rowBase + rt * 16 + q * 4 + r;
                if (row < N) out[(size_t)row * D + col] = bf16_rne(acc[rt][ct][r]);
            }
        }
    }
}

// ---------------- fused: per-bucket dis (blocks 0..NB) + GEMM1 (blocks NB..) ----------------
// dis blocks stream their bucket's tmp slot once (sequential, mostly L2-warm),
// accumulate weighted in-degree in LDS, write dis = rsqrt(1+wsum).

__global__ __launch_bounds__(256) void k_disA_g1(const unsigned long long* __restrict__ tmp,
                                                 const int* __restrict__ gCursor,
                                                 float* __restrict__ dis,
                                                 const float* __restrict__ x,
                                                 const unsigned int* __restrict__ Wt1,
                                                 unsigned short* __restrict__ A) {
    __shared__ SMem sm;
    const int t = threadIdx.x;
    if (blockIdx.x < NB) {
        const int bk = blockIdx.x;
        if (t < BUCKET) sm.wsumL[t] = 0.f;
        __syncthreads();
        const size_t segBeg = (size_t)bk * CAP;
        int segLen = gCursor[bk];
        if (segLen > CAP) segLen = CAP;
        for (int e = t; e < segLen; e += 256) {
            unsigned long long rec = tmp[segBeg + e];
            atomicAdd(&sm.wsumL[(int)(rec & (BUCKET - 1))],
                      __uint_as_float((unsigned int)(rec >> 32)));
        }
        __syncthreads();
        if (t < BUCKET) {
            int node = bk * BUCKET + t;
            if (node < N) dis[node] = rsqrtf(1.0f + sm.wsumL[t]);
        }
    } else {
        gemm_mfma_body(sm.Ws, x, Wt1, A, blockIdx.x - NB);
    }
}

// ---------------- fused sort+aggregate: block (512 thr) per bucket ----------------
// Records live in REGISTERS (<=6/thread since CAP = 512*6): phase0 counts via LDS
// atomics; prefix -> offL, rowStart/rowLen, needed worklist; phase1 scatters
// (src, ew*dis[src]) into LDS (global pairs only for masked dsts); phase2: waves
// pop needed nodes from the worklist and gather-aggregate (8-deep + scalar -- the
// R9-proven body; deeper tiers cost VALU, R10).

__global__ __launch_bounds__(512) void k_sort_agg(const unsigned long long* __restrict__ tmp,
                                                  const int* __restrict__ gCursor,
                                                  const float* __restrict__ dis,
                                                  const unsigned int* __restrict__ needed,
                                                  const unsigned int* __restrict__ maskbit,
                                                  const float* __restrict__ b,
                                                  const unsigned int* __restrict__ Hb,
                                                  int* __restrict__ rowStart,
                                                  int* __restrict__ rowLen,
                                                  int2* __restrict__ pairs,
                                                  unsigned int* __restrict__ outB) {
    __shared__ int2 lp[CAP];
    __shared__ int cnt[BUCKET];
    __shared__ int offL[BUCKET + 1];
    __shared__ int wl[BUCKET];
    __shared__ int waveS[2];
    __shared__ int nw, wcur;
    const int bk = blockIdx.x;
    const int t = threadIdx.x;
    const size_t segBeg = (size_t)bk * CAP;
    int segLen = gCursor[bk];
    if (segLen > CAP) segLen = CAP;   // matches k_part's overflow guard

    if (t == 0) { nw = 0; wcur = 0; offL[BUCKET] = segLen; }
    if (t < BUCKET) cnt[t] = 0;
    const uint4 mb4 = ((const uint4*)maskbit)[bk];   // this bucket's 128 mask bits
    __syncthreads();

    // phase 0: load records into registers, count per local-dst
    unsigned long long r_[6];
#pragma unroll
    for (int i = 0; i < 6; ++i) {
        int e = t + i * 512;
        if (e < segLen) {
            r_[i] = tmp[segBeg + e];
            atomicAdd(&cnt[(int)(r_[i] & (BUCKET - 1))], 1);
        }
    }
    __syncthreads();

    // prefix over cnt (threads 0..127), rowStart/rowLen, worklist build
    const int lane = t & 63;
    {
        const int wv2 = t >> 6;
        const int pv = (t < BUCKET) ? cnt[t] : 0;
        int v = pv;
        for (int o = 1; o < 64; o <<= 1) {
            int u = __shfl_up(v, o);
            if (lane >= o) v += u;
        }
        if (lane == 63 && wv2 < 2) waveS[wv2] = v;
        __syncthreads();
        if (t < BUCKET) {
            const int wb = (wv2 == 1) ? waveS[0] : 0;
            const int ex = wb + v - pv;
            offL[t] = ex;
            const int node = bk * BUCKET + t;
            if (node < N) {
                rowStart[node] = (int)segBeg + ex;
                rowLen[node] = pv;
                if ((needed[node >> 5] >> (node & 31)) & 1u) {
                    int r = atomicAdd(&nw, 1);
                    wl[r] = t;
                }
            }
            cnt[t] = 0;
        }
    }
    __syncthreads();

    // phase 1: scatter registers -> LDS (prescaled); global pairs only for masked dsts
#pragma unroll
    for (int i = 0; i < 6; ++i) {
        int e = t + i * 512;
        if (e < segLen) {
            unsigned long long rec = r_[i];
            int dl = (int)(rec & (BUCKET - 1));
            int s  = (int)((rec >> NBITS) & 0xFFFFF);
            float w = __uint_as_float((unsigned int)(rec >> 32));
            float v = w * dis[s];             // per-thread gather, 64 edges/instr
            int r = atomicAdd(&cnt[dl], 1);
            int pos = offL[dl] + r;
            int2 pr = make_int2(s, __float_as_int(v));
            lp[pos] = pr;
            unsigned int mw = (dl < 32) ? mb4.x : (dl < 64) ? mb4.y : (dl < 96) ? mb4.z : mb4.w;
            if ((mw >> (dl & 31)) & 1u) pairs[segBeg + pos] = pr;
        }
    }
    __syncthreads();

    // phase 2: waves pop needed nodes from the worklist
    for (;;) {
        int idx;
        if (lane == 0) idx = atomicAdd(&wcur, 1);
        idx = __shfl(idx, 0);
        if (idx >= nw) break;
        const int nl = wl[idx];
        const int node = bk * BUCKET + nl;
        const int beg = offL[nl], end = offL[nl + 1];
        float ax = 0.f, ay = 0.f;
        int j = beg;
        for (; j + 7 < end; j += 8) {
            int2 p[8];
            unsigned int h[8];
#pragma unroll
            for (int i = 0; i < 8; ++i) p[i] = lp[j + i];
#pragma unroll
            for (int i = 0; i < 8; ++i) h[i] = Hb[(size_t)p[i].x * 64 + lane];
#pragma unroll
            for (int i = 0; i < 8; ++i) {
                float v = __int_as_float(p[i].y);
                ax += bf16_lo(h[i]) * v;
                ay += bf16_hi(h[i]) * v;
            }
        }
        for (; j < end; ++j) {
            int2 p0 = lp[j];
            unsigned int h0 = Hb[(size_t)p0.x * 64 + lane];
            float v0 = __int_as_float(p0.y);
            ax += bf16_lo(h0) * v0;
            ay += bf16_hi(h0) * v0;
        }
        float dd = dis[node];
        float sn = dd * dd;  // self-loop norm = 1/deg
        unsigned int hs = Hb[(size_t)node * 64 + lane];
        float2 bb = ((const float2*)b)[lane];
        float ox = fmaxf(ax * dd + bf16_lo(hs) * sn + bb.x, 0.f);
        float oy = fmaxf(ay * dd + bf16_hi(hs) * sn + bb.y, 0.f);
        __builtin_nontemporal_store(pack_bf16x2(ox, oy), outB + (size_t)node * 64 + lane);
    }
}

// ---------------- fused layer-2 at mask nodes: out = agg(B)@W2 + b2 ----------------
// (agg is linear, so agg(B@W2) = agg(B)@W2.) Wave per mask row: gather-aggregate B,
// park the row in LDS, then multiply by W2 staged in LDS (two 64-row halves).

__global__ __launch_bounds__(256) void k_mask_out(const unsigned int* __restrict__ Hb,
                                                  const int2* __restrict__ pairs,
                                                  const int* __restrict__ rowStart,
                                                  const int* __restrict__ rowLen,
                                                  const float* __restrict__ dis,
                                                  const float* __restrict__ W2,
                                                  const float* __restrict__ b2,
                                                  const int* __restrict__ mask,
                                                  const int* __restrict__ y,
                                                  float* __restrict__ out) {
    __shared__ float w2s[64 * 132];   // 132 stride: float4-aligned stores, bank spread
    __shared__ float rowL[4][128];
    const int t = threadIdx.x;
    const int wv = t >> 6, lane = t & 63;
    const int i = blockIdx.x * 4 + wv;   // grid = M/4 exactly (1250*4 = 5000)
    const int node = mask[i];
    const int beg = rowStart[node], end = beg + rowLen[node];

    float ax = 0.f, ay = 0.f;
    int j = beg;
    for (; j + 7 < end; j += 8) {
        int2 p[8];
        unsigned int h[8];
#pragma unroll
        for (int ii = 0; ii < 8; ++ii) p[ii] = pairs[j + ii];
#pragma unroll
        for (int ii = 0; ii < 8; ++ii) h[ii] = Hb[(size_t)p[ii].x * 64 + lane];
#pragma unroll
        for (int ii = 0; ii < 8; ++ii) {
            float v = __int_as_float(p[ii].y);
            ax += bf16_lo(h[ii]) * v;
            ay += bf16_hi(h[ii]) * v;
        }
    }
    for (; j < end; ++j) {
        int2 p0 = pairs[j];
        unsigned int h0 = Hb[(size_t)p0.x * 64 + lane];
        float v0 = __int_as_float(p0.y);
        ax += bf16_lo(h0) * v0;
        ay += bf16_hi(h0) * v0;
    }
    {
        float dd = dis[node];
        float sn = dd * dd;
        unsigned int hs = Hb[(size_t)node * 64 + lane];
        rowL[wv][2 * lane]     = ax * dd + bf16_lo(hs) * sn;   // bias b2 added post-GEMM
        rowL[wv][2 * lane + 1] = ay * dd + bf16_hi(hs) * sn;
    }

    float2 bb = ((const float2*)b2)[lane];
    float acc0 = bb.x, acc1 = bb.y;
#pragma unroll
    for (int h0 = 0; h0 < 2; ++h0) {
        __syncthreads();
        for (int idx = t; idx < 2048; idx += 256) {   // stage 64 rows of W2 (float4 units)
            float4 v = ((const float4*)W2)[h0 * 2048 + idx];
            int k = (idx * 4) >> 7, n = (idx * 4) & 127;
            *(float4*)(&w2s[k * 132 + n]) = v;
        }
        __syncthreads();
#pragma unroll 8
        for (int k = 0; k < 64; ++k) {
            float a = rowL[wv][h0 * 64 + k];
            float2 w = *(const float2*)(&w2s[k * 132 + 2 * lane]);
            acc0 += a * w.x;
            acc1 += a * w.y;
        }
    }
    ((float2*)(out + (size_t)i * D))[lane] = make_float2(acc0, acc1);
    if (lane == 0) out[(size_t)M * D + i] = (float)y[node];
}

extern "C" void kernel_launch(void* const* d_in, const int* in_sizes, int n_in,
                              void* d_out, int out_size, void* d_ws, size_t ws_size,
                              hipStream_t stream) {
    const float* x  = (const float*)d_in[0];
    const float* ew = (const float*)d_in[1];
    const float* W1 = (const float*)d_in[2];
    const float* b1 = (const float*)d_in[3];
    const float* W2 = (const float*)d_in[4];
    const float* b2 = (const float*)d_in[5];
    const int* eidx = (const int*)d_in[6];
    const int* mask = (const int*)d_in[7];
    const int* y    = (const int*)d_in[8];
    const int* src = eidx;       // edge_index[0]
    const int* dst = eidx + E;   // edge_index[1]

    // Workspace layout (bytes):
    //   dis       @ 0        : N f32        (0.4 MB)
    //   rowStart  @ 512 KB   : N i32        (0.4 MB)
    //   rowLen    @ 1024 KB  : N i32        (0.4 MB)
    //   maskbit   @ 1440 KB  : 16 KB bitmap }
    //   needed    @ 1456 KB  : 16 KB bitmap }  zeroed together (36 KB memset,
    //   gCursor   @ 1472 KB  : NB i32       }   covers relative cursors too)
    //   Wt1       @ 1480 KB  : 8192 u32    (32 KB)
    //   pairs     @ 2 MB     : NB*CAP int2 (19.2 MB, sparsely written)
    //   tmp       @ 22 MB    : NB*CAP u64  (19.2 MB)
    //   A  (bf16) @ 42 MB    : N*D bf16    (25.6 MB)
    //   B  (bf16) @ 68 MB    : N*D bf16    (25.6 MB)   total ~94 MB
    char* ws = (char*)d_ws;
    float* dis      = (float*)(ws);
    int*   rowStart = (int*)(ws + (size_t)512 * 1024);
    int*   rowLen   = (int*)(ws + (size_t)1024 * 1024);
    unsigned int* maskbit = (unsigned int*)(ws + (size_t)1440 * 1024);
    unsigned int* needed  = (unsigned int*)(ws + (size_t)1456 * 1024);
    int*   gCursor  = (int*)(ws + (size_t)1472 * 1024);
    unsigned int* Wt1 = (unsigned int*)(ws + (size_t)1480 * 1024);
    int2*  pairs    = (int2*)(ws + (size_t)2 * 1024 * 1024);
    unsigned long long* tmp = (unsigned long long*)(ws + (size_t)22 * 1024 * 1024);
    unsigned short* A  = (unsigned short*)(ws + (size_t)42 * 1024 * 1024);
    unsigned short* B  = (unsigned short*)(ws + (size_t)68 * 1024 * 1024);

    // --- zero bitmaps + relative cursors ---
    (void)hipMemsetAsync(ws + (size_t)1440 * 1024, 0, (size_t)36 * 1024, stream);

    // --- W1 prep + maskbit/needed seed (maskbit must precede k_part's scan) ---
    hipLaunchKernelGGL(k_misc0, dim3(PREP_BLKS + MB_BLKS), dim3(256), 0, stream,
                       W1, Wt1, mask, maskbit, needed);

    // --- partition via atomic run reservation + needed-set scan ---
    hipLaunchKernelGGL(k_part, dim3(NPP), dim3(1024), 0, stream,
                       src, dst, ew, gCursor, tmp, maskbit, needed);

    // --- per-bucket dis (LDS accumulation over tmp slots) fused with GEMM1 ---
    hipLaunchKernelGGL(k_disA_g1, dim3(NB + MF_BLKS), dim3(256), 0, stream,
                       tmp, gCursor, dis, x, Wt1, A);

    // --- fused sort + layer-1 aggregate: B = relu(agg(A) + b1); pairs for masked dsts ---
    hipLaunchKernelGGL(k_sort_agg, dim3(NB), dim3(512), 0, stream,
                       tmp, gCursor, dis, needed, maskbit, b1,
                       (const unsigned int*)A, rowStart, rowLen, pairs, (unsigned int*)B);

    // --- fused layer-2 at mask nodes: out = agg(B)@W2 + b2 (+ labels) ---
    hipLaunchKernelGGL(k_mask_out, dim3(M / 4), dim3(256), 0, stream,
                       (const unsigned int*)B, pairs, rowStart, rowLen, dis, W2, b2,
                       mask, y, (float*)d_out);
}

// Round 13
// 237.376 us; speedup vs baseline: 1.0797x; 1.0056x over previous
//
#include <hip/hip_runtime.h>

// Problem constants (fixed by the reference).
constexpr int N = 100000;   // nodes
constexpr int E = 1600000;  // edges
constexpr int D = 128;      // feature dim (both layers)
constexpr int M = 5000;     // mask size

constexpr int MF_BLKS = (N + 255) / 256;           // 391 mfma-gemm blocks (256 rows each)

// Counting-sort CSR build parameters.
// Bucket = dst>>7 (128 nodes) -> 782 buckets, each with a FIXED 3072-record slot in
// tmp/pairs: counts are Binomial(1.6M, 1/782) = 2046 +/- 45, CAP is +22 sigma.
// No histogram, no scan; cursors are RELATIVE (start 0, zeroed by the memset).
// R8: per-dst global float atomics cost ~70us (never again).
// R10: gather tiers beyond 8-deep add VALU cost, no win.
// R11: needed-scan must stay in k_part (high TLP). R13: its maskbit dependency is
// removed via a block-local LDS bitmap built from mask[] directly -> k_misc0 deleted
// (W1-prep + global bitmap seeding ride along k_part; consumers are 1-2 launches later).
constexpr int NBITS = 7;
constexpr int BUCKET = 1 << NBITS;                 // 128 nodes per bucket
constexpr int NB  = (N + BUCKET - 1) / BUCKET;     // 782 buckets
constexpr int CAP = 3072;                          // records per bucket slot
constexpr int EBP = 4096;                          // edges per partition block
constexpr int NPP = (E + EBP - 1) / EBP;           // 391 partition blocks (1024 thr each)
constexpr int PREP_BLKS = 8;                       // W1-prep ride-along blocks (1024 thr)
constexpr int MB_BLKS = (M + 1023) / 1024;         // 5 mask-seed ride-along blocks
constexpr int MBW = 4096;                          // LDS maskbit words (131072 bits >= N)

typedef __attribute__((ext_vector_type(8))) short bf16x8;
typedef __attribute__((ext_vector_type(4))) float f32x4;

// ---------------- bf16 helpers (RNE pack, cheap unpack) ----------------

__device__ __forceinline__ unsigned int pack_bf16x2(float a, float b) {
    unsigned int ua = __float_as_uint(a);
    unsigned int ub = __float_as_uint(b);
    ua = (ua + 0x7FFFu + ((ua >> 16) & 1u)) >> 16;
    ub = (ub + 0x7FFFu + ((ub >> 16) & 1u)) & 0xFFFF0000u;
    return ua | ub;
}
__device__ __forceinline__ unsigned short bf16_rne(float a) {
    unsigned int ua = __float_as_uint(a);
    return (unsigned short)((ua + 0x7FFFu + ((ua >> 16) & 1u)) >> 16);
}
__device__ __forceinline__ float bf16_lo(unsigned int u) { return __uint_as_float(u << 16); }
__device__ __forceinline__ float bf16_hi(unsigned int u) { return __uint_as_float(u & 0xFFFF0000u); }

// ---------------- partition (+ W1-prep, mask-seed ride-alongs) ----------------
// record: bits[6:0]=d&127, bits[26:7]=src, bits[63:32]=ew bits.
// Cursors bucket-relative (zeroed by memset); pos = b*CAP + off+r.
// needed-scan uses a BLOCK-LOCAL LDS maskbit built from mask[] (5000 ints, L2
// broadcast) -- no dependency on the global bitmap, so no preceding kernel.
// Global maskbit/needed seeds ride along (consumed by k_sort_agg, 2 launches later).

__global__ __launch_bounds__(1024) void k_part(const int* __restrict__ src,
                                               const int* __restrict__ dst,
                                               const float* __restrict__ ew,
                                               int* __restrict__ gCursor,
                                               unsigned long long* __restrict__ tmp,
                                               const int* __restrict__ mask,
                                               unsigned int* __restrict__ maskbit,
                                               unsigned int* __restrict__ needed,
                                               const float* __restrict__ W1,
                                               unsigned int* __restrict__ Wt1) {
    __shared__ int cnt[NB];
    __shared__ int off[NB];
    __shared__ int rk[NB];
    __shared__ unsigned int mbit[MBW];
    const int t = threadIdx.x;

    if (blockIdx.x >= NPP) {
        const int bi = blockIdx.x - NPP;
        if (bi < PREP_BLKS) {
            int idx = bi * 1024 + t;   // 8192 total (W1 only; W2 used in fp32)
            if (idx < 8192) {
                int n = idx >> 6, kk = idx & 63;
                float a = W1[(2 * kk) * D + n];
                float b = W1[(2 * kk + 1) * D + n];
                Wt1[idx] = pack_bf16x2(a, b);
            }
        } else {
            int i = (bi - PREP_BLKS) * 1024 + t;
            if (i < M) {
                int n = mask[i];
                atomicOr(&maskbit[n >> 5], 1u << (n & 31));
                atomicOr(&needed[n >> 5], 1u << (n & 31));  // masked nodes need their row
            }
        }
        return;
    }

    for (int i = t; i < NB; i += 1024) { cnt[i] = 0; rk[i] = 0; }
    for (int i = t; i < MBW; i += 1024) mbit[i] = 0;
    __syncthreads();

    // build block-local maskbit (overlaps with the record loads below)
    for (int i = t; i < M; i += 1024) {
        int n = mask[i];
        atomicOr(&mbit[n >> 5], 1u << (n & 31));
    }

    const int eb = blockIdx.x * EBP;
    int d_[4], s_[4];
    float w_[4];
#pragma unroll
    for (int i = 0; i < 4; ++i) {
        int e = eb + t + i * 1024;
        if (e < E) {
            d_[i] = __builtin_nontemporal_load(dst + e);
            s_[i] = __builtin_nontemporal_load(src + e);
            w_[i] = __builtin_nontemporal_load(ew + e);
            atomicAdd(&cnt[d_[i] >> NBITS], 1);
        } else {
            d_[i] = -1;
        }
    }
    __syncthreads();

    for (int i = t; i < NB; i += 1024) {
        int c = cnt[i];
        if (c > 0) off[i] = atomicAdd(&gCursor[i], c);   // relative reservation
    }
    __syncthreads();

#pragma unroll
    for (int i = 0; i < 4; ++i) {
        if (d_[i] >= 0) {
            int b = d_[i] >> NBITS;
            int r = atomicAdd(&rk[b], 1);
            int posr = off[b] + r;
            if (posr < CAP) {   // overflow guard (+22 sigma; never expected)
                unsigned long long rec =
                    ((unsigned long long)(unsigned int)__float_as_int(w_[i]) << 32) |
                    ((unsigned int)s_[i] << NBITS) | (unsigned int)(d_[i] & (BUCKET - 1));
                tmp[(size_t)b * CAP + posr] = rec;   // cached: L2 merges the ~42B runs
            }
            if ((mbit[d_[i] >> 5] >> (d_[i] & 31)) & 1u)
                atomicOr(&needed[s_[i] >> 5], 1u << (s_[i] & 31));
        }
    }
}

// ---------------- shared-memory union: GEMM W-tile OR dis-accumulation array ----------------

union SMem {
    unsigned int Ws[128 * 68];
    float wsumL[BUCKET];
};

// ---------------- MFMA GEMM body: 256 rows/block, 4 waves; wave = 64 rows x 128 cols ----------------
// A-frag: A[m=lane&15][k=quad*8+j]; B-frag: B[k=quad*8+j][n=lane&15];
// D: col=lane&15, row=quad*4+reg  (HW-verified layouts, 16x16x32 bf16).
// W^T staged in LDS with 68-uint row stride (bank-conflict padding).

__device__ __forceinline__ void gemm_mfma_body(unsigned int* __restrict__ Ws,
                                               const float* __restrict__ Xin,
                                               const unsigned int* __restrict__ Wt,
                                               unsigned short* __restrict__ out, int blk) {
    const int t = threadIdx.x;
#pragma unroll
    for (int i = 0; i < 8; ++i) {
        int f4 = t + i * 256;        // uint4 index, 2048 total
        int n = f4 >> 4;
        int k4 = f4 & 15;
        uint4 w = ((const uint4*)Wt)[f4];
        *(uint4*)(&Ws[n * 68 + k4 * 4]) = w;
    }
    __syncthreads();

    const int wv = t >> 6, lane = t & 63;
    const int q = lane >> 4, l15 = lane & 15;
    const int rowBase = blk * 256 + wv * 64;

    f32x4 acc[4][8] = {};
#pragma unroll
    for (int kc = 0; kc < 4; ++kc) {
        bf16x8 af[4];
#pragma unroll
        for (int rt = 0; rt < 4; ++rt) {
            int row = rowBase + rt * 16 + l15;
            if (row > N - 1) row = N - 1;   // tail: duplicate last row, stores guarded
            union { uint4 u; bf16x8 v; } cv;
            const float* xr = Xin + (size_t)row * D + kc * 32 + q * 8;
            float4 x0 = *(const float4*)xr;
            float4 x1 = *(const float4*)(xr + 4);
            cv.u.x = pack_bf16x2(x0.x, x0.y);
            cv.u.y = pack_bf16x2(x0.z, x0.w);
            cv.u.z = pack_bf16x2(x1.x, x1.y);
            cv.u.w = pack_bf16x2(x1.z, x1.w);
            af[rt] = cv.v;
        }
#pragma unroll
        for (int ct = 0; ct < 8; ++ct) {
            union { uint4 u; bf16x8 v; } bv;
            bv.u = *(const uint4*)(&Ws[(ct * 16 + l15) * 68 + kc * 16 + q * 4]);
#pragma unroll
            for (int rt = 0; rt < 4; ++rt)
                acc[rt][ct] = __builtin_amdgcn_mfma_f32_16x16x32_bf16(af[rt], bv.v, acc[rt][ct], 0, 0, 0);
        }
    }

#pragma unroll
    for (int rt = 0; rt < 4; ++rt) {
#pragma unroll
        for (int ct = 0; ct < 8; ++ct) {
            int col = ct * 16 + l15;
#pragma unroll
            for (int r = 0; r < 4; ++r) {
                int row = rowBase + rt * 16 + q * 4 + r;
                if (row < N) out[(size_t)row * D + col] = bf16_rne(acc[rt][ct][r]);
            }
        }
    }
}

// ---------------- fused: per-bucket dis (blocks 0..NB) + GEMM1 (blocks NB..) ----------------
// dis blocks stream their bucket's tmp slot once (sequential, mostly L2-warm),
// accumulate weighted in-degree in LDS, write dis = rsqrt(1+wsum).

__global__ __launch_bounds__(256) void k_disA_g1(const unsigned long long* __restrict__ tmp,
                                                 const int* __restrict__ gCursor,
                                                 float* __restrict__ dis,
                                                 const float* __restrict__ x,
                                                 const unsigned int* __restrict__ Wt1,
                                                 unsigned short* __restrict__ A) {
    __shared__ SMem sm;
    const int t = threadIdx.x;
    if (blockIdx.x < NB) {
        const int bk = blockIdx.x;
        if (t < BUCKET) sm.wsumL[t] = 0.f;
        __syncthreads();
        const size_t segBeg = (size_t)bk * CAP;
        int segLen = gCursor[bk];
        if (segLen > CAP) segLen = CAP;
        for (int e = t; e < segLen; e += 256) {
            unsigned long long rec = tmp[segBeg + e];
            atomicAdd(&sm.wsumL[(int)(rec & (BUCKET - 1))],
                      __uint_as_float((unsigned int)(rec >> 32)));
        }
        __syncthreads();
        if (t < BUCKET) {
            int node = bk * BUCKET + t;
            if (node < N) dis[node] = rsqrtf(1.0f + sm.wsumL[t]);
        }
    } else {
        gemm_mfma_body(sm.Ws, x, Wt1, A, blockIdx.x - NB);
    }
}

// ---------------- fused sort+aggregate: block (1024 thr, 16 waves) per bucket ----------------
// R13: 1024 threads/block. At 512 thr the 782-block grid (~3.05/CU) cannot fill the
// 4-block/CU thread cap (75% ceiling, 47% measured); at 1024 thr the cap is 2
// blocks/CU = 32 waves/CU (100%), and 782 > 512 co-resident keeps CUs fed.
// Records in REGISTERS (<=3/thread); phase0 counts via LDS atomics; prefix -> offL,
// rowStart/rowLen, needed worklist; phase1 scatters (src, ew*dis[src]) into LDS
// (global pairs only for masked dsts); phase2: waves pop needed nodes (8-deep body).

__global__ __launch_bounds__(1024) void k_sort_agg(const unsigned long long* __restrict__ tmp,
                                                   const int* __restrict__ gCursor,
                                                   const float* __restrict__ dis,
                                                   const unsigned int* __restrict__ needed,
                                                   const unsigned int* __restrict__ maskbit,
                                                   const float* __restrict__ b,
                                                   const unsigned int* __restrict__ Hb,
                                                   int* __restrict__ rowStart,
                                                   int* __restrict__ rowLen,
                                                   int2* __restrict__ pairs,
                                                   unsigned int* __restrict__ outB) {
    __shared__ int2 lp[CAP];
    __shared__ int cnt[BUCKET];
    __shared__ int offL[BUCKET + 1];
    __shared__ int wl[BUCKET];
    __shared__ int waveS[2];
    __shared__ int nw, wcur;
    const int bk = blockIdx.x;
    const int t = threadIdx.x;
    const size_t segBeg = (size_t)bk * CAP;
    int segLen = gCursor[bk];
    if (segLen > CAP) segLen = CAP;   // matches k_part's overflow guard

    if (t == 0) { nw = 0; wcur = 0; offL[BUCKET] = segLen; }
    if (t < BUCKET) cnt[t] = 0;
    const uint4 mb4 = ((const uint4*)maskbit)[bk];   // this bucket's 128 mask bits
    __syncthreads();

    // phase 0: load records into registers, count per local-dst
    unsigned long long r_[3];
#pragma unroll
    for (int i = 0; i < 3; ++i) {
        int e = t + i * 1024;
        if (e < segLen) {
            r_[i] = tmp[segBeg + e];
            atomicAdd(&cnt[(int)(r_[i] & (BUCKET - 1))], 1);
        }
    }
    __syncthreads();

    // prefix over cnt (threads 0..127), rowStart/rowLen, worklist build
    const int lane = t & 63;
    {
        const int wv2 = t >> 6;
        const int pv = (t < BUCKET) ? cnt[t] : 0;
        int v = pv;
        for (int o = 1; o < 64; o <<= 1) {
            int u = __shfl_up(v, o);
            if (lane >= o) v += u;
        }
        if (lane == 63 && wv2 < 2) waveS[wv2] = v;
        __syncthreads();
        if (t < BUCKET) {
            const int wb = (wv2 == 1) ? waveS[0] : 0;
            const int ex = wb + v - pv;
            offL[t] = ex;
            const int node = bk * BUCKET + t;
            if (node < N) {
                rowStart[node] = (int)segBeg + ex;
                rowLen[node] = pv;
                if ((needed[node >> 5] >> (node & 31)) & 1u) {
                    int r = atomicAdd(&nw, 1);
                    wl[r] = t;
                }
            }
            cnt[t] = 0;
        }
    }
    __syncthreads();

    // phase 1: scatter registers -> LDS (prescaled); global pairs only for masked dsts
#pragma unroll
    for (int i = 0; i < 3; ++i) {
        int e = t + i * 1024;
        if (e < segLen) {
            unsigned long long rec = r_[i];
            int dl = (int)(rec & (BUCKET - 1));
            int s  = (int)((rec >> NBITS) & 0xFFFFF);
            float w = __uint_as_float((unsigned int)(rec >> 32));
            float v = w * dis[s];             // per-thread gather, 64 edges/instr
            int r = atomicAdd(&cnt[dl], 1);
            int pos = offL[dl] + r;
            int2 pr = make_int2(s, __float_as_int(v));
            lp[pos] = pr;
            unsigned int mw = (dl < 32) ? mb4.x : (dl < 64) ? mb4.y : (dl < 96) ? mb4.z : mb4.w;
            if ((mw >> (dl & 31)) & 1u) pairs[segBeg + pos] = pr;
        }
    }
    __syncthreads();

    // phase 2: waves pop needed nodes from the worklist
    for (;;) {
        int idx;
        if (lane == 0) idx = atomicAdd(&wcur, 1);
        idx = __shfl(idx, 0);
        if (idx >= nw) break;
        const int nl = wl[idx];
        const int node = bk * BUCKET + nl;
        const int beg = offL[nl], end = offL[nl + 1];
        float ax = 0.f, ay = 0.f;
        int j = beg;
        for (; j + 7 < end; j += 8) {
            int2 p[8];
            unsigned int h[8];
#pragma unroll
            for (int i = 0; i < 8; ++i) p[i] = lp[j + i];
#pragma unroll
            for (int i = 0; i < 8; ++i) h[i] = Hb[(size_t)p[i].x * 64 + lane];
#pragma unroll
            for (int i = 0; i < 8; ++i) {
                float v = __int_as_float(p[i].y);
                ax += bf16_lo(h[i]) * v;
                ay += bf16_hi(h[i]) * v;
            }
        }
        for (; j < end; ++j) {
            int2 p0 = lp[j];
            unsigned int h0 = Hb[(size_t)p0.x * 64 + lane];
            float v0 = __int_as_float(p0.y);
            ax += bf16_lo(h0) * v0;
            ay += bf16_hi(h0) * v0;
        }
        float dd = dis[node];
        float sn = dd * dd;  // self-loop norm = 1/deg
        unsigned int hs = Hb[(size_t)node * 64 + lane];
        float2 bb = ((const float2*)b)[lane];
        float ox = fmaxf(ax * dd + bf16_lo(hs) * sn + bb.x, 0.f);
        float oy = fmaxf(ay * dd + bf16_hi(hs) * sn + bb.y, 0.f);
        __builtin_nontemporal_store(pack_bf16x2(ox, oy), outB + (size_t)node * 64 + lane);
    }
}

// ---------------- fused layer-2 at mask nodes: out = agg(B)@W2 + b2 ----------------
// (agg is linear, so agg(B@W2) = agg(B)@W2.) Wave per mask row: gather-aggregate B,
// park the row in LDS, then multiply by W2 staged in LDS (two 64-row halves).

__global__ __launch_bounds__(256) void k_mask_out(const unsigned int* __restrict__ Hb,
                                                  const int2* __restrict__ pairs,
                                                  const int* __restrict__ rowStart,
                                                  const int* __restrict__ rowLen,
                                                  const float* __restrict__ dis,
                                                  const float* __restrict__ W2,
                                                  const float* __restrict__ b2,
                                                  const int* __restrict__ mask,
                                                  const int* __restrict__ y,
                                                  float* __restrict__ out) {
    __shared__ float w2s[64 * 132];   // 132 stride: float4-aligned stores, bank spread
    __shared__ float rowL[4][128];
    const int t = threadIdx.x;
    const int wv = t >> 6, lane = t & 63;
    const int i = blockIdx.x * 4 + wv;   // grid = M/4 exactly (1250*4 = 5000)
    const int node = mask[i];
    const int beg = rowStart[node], end = beg + rowLen[node];

    float ax = 0.f, ay = 0.f;
    int j = beg;
    for (; j + 7 < end; j += 8) {
        int2 p[8];
        unsigned int h[8];
#pragma unroll
        for (int ii = 0; ii < 8; ++ii) p[ii] = pairs[j + ii];
#pragma unroll
        for (int ii = 0; ii < 8; ++ii) h[ii] = Hb[(size_t)p[ii].x * 64 + lane];
#pragma unroll
        for (int ii = 0; ii < 8; ++ii) {
            float v = __int_as_float(p[ii].y);
            ax += bf16_lo(h[ii]) * v;
            ay += bf16_hi(h[ii]) * v;
        }
    }
    for (; j < end; ++j) {
        int2 p0 = pairs[j];
        unsigned int h0 = Hb[(size_t)p0.x * 64 + lane];
        float v0 = __int_as_float(p0.y);
        ax += bf16_lo(h0) * v0;
        ay += bf16_hi(h0) * v0;
    }
    {
        float dd = dis[node];
        float sn = dd * dd;
        unsigned int hs = Hb[(size_t)node * 64 + lane];
        rowL[wv][2 * lane]     = ax * dd + bf16_lo(hs) * sn;   // bias b2 added post-GEMM
        rowL[wv][2 * lane + 1] = ay * dd + bf16_hi(hs) * sn;
    }

    float2 bb = ((const float2*)b2)[lane];
    float acc0 = bb.x, acc1 = bb.y;
#pragma unroll
    for (int h0 = 0; h0 < 2; ++h0) {
        __syncthreads();
        for (int idx = t; idx < 2048; idx += 256) {   // stage 64 rows of W2 (float4 units)
            float4 v = ((const float4*)W2)[h0 * 2048 + idx];
            int k = (idx * 4) >> 7, n = (idx * 4) & 127;
            *(float4*)(&w2s[k * 132 + n]) = v;
        }
        __syncthreads();
#pragma unroll 8
        for (int k = 0; k < 64; ++k) {
            float a = rowL[wv][h0 * 64 + k];
            float2 w = *(const float2*)(&w2s[k * 132 + 2 * lane]);
            acc0 += a * w.x;
            acc1 += a * w.y;
        }
    }
    ((float2*)(out + (size_t)i * D))[lane] = make_float2(acc0, acc1);
    if (lane == 0) out[(size_t)M * D + i] = (float)y[node];
}

extern "C" void kernel_launch(void* const* d_in, const int* in_sizes, int n_in,
                              void* d_out, int out_size, void* d_ws, size_t ws_size,
                              hipStream_t stream) {
    const float* x  = (const float*)d_in[0];
    const float* ew = (const float*)d_in[1];
    const float* W1 = (const float*)d_in[2];
    const float* b1 = (const float*)d_in[3];
    const float* W2 = (const float*)d_in[4];
    const float* b2 = (const float*)d_in[5];
    const int* eidx = (const int*)d_in[6];
    const int* mask = (const int*)d_in[7];
    const int* y    = (const int*)d_in[8];
    const int* src = eidx;       // edge_index[0]
    const int* dst = eidx + E;   // edge_index[1]

    // Workspace layout (bytes):
    //   dis       @ 0        : N f32        (0.4 MB)
    //   rowStart  @ 512 KB   : N i32        (0.4 MB)
    //   rowLen    @ 1024 KB  : N i32        (0.4 MB)
    //   maskbit   @ 1440 KB  : 16 KB bitmap }
    //   needed    @ 1456 KB  : 16 KB bitmap }  zeroed together (36 KB memset,
    //   gCursor   @ 1472 KB  : NB i32       }   covers relative cursors too)
    //   Wt1       @ 1480 KB  : 8192 u32    (32 KB)
    //   pairs     @ 2 MB     : NB*CAP int2 (19.2 MB, sparsely written)
    //   tmp       @ 22 MB    : NB*CAP u64  (19.2 MB)
    //   A  (bf16) @ 42 MB    : N*D bf16    (25.6 MB)
    //   B  (bf16) @ 68 MB    : N*D bf16    (25.6 MB)   total ~94 MB
    char* ws = (char*)d_ws;
    float* dis      = (float*)(ws);
    int*   rowStart = (int*)(ws + (size_t)512 * 1024);
    int*   rowLen   = (int*)(ws + (size_t)1024 * 1024);
    unsigned int* maskbit = (unsigned int*)(ws + (size_t)1440 * 1024);
    unsigned int* needed  = (unsigned int*)(ws + (size_t)1456 * 1024);
    int*   gCursor  = (int*)(ws + (size_t)1472 * 1024);
    unsigned int* Wt1 = (unsigned int*)(ws + (size_t)1480 * 1024);
    int2*  pairs    = (int2*)(ws + (size_t)2 * 1024 * 1024);
    unsigned long long* tmp = (unsigned long long*)(ws + (size_t)22 * 1024 * 1024);
    unsigned short* A  = (unsigned short*)(ws + (size_t)42 * 1024 * 1024);
    unsigned short* B  = (unsigned short*)(ws + (size_t)68 * 1024 * 1024);

    // --- zero bitmaps + relative cursors ---
    (void)hipMemsetAsync(ws + (size_t)1440 * 1024, 0, (size_t)36 * 1024, stream);

    // --- partition + needed-scan (LDS-local maskbit) + W1-prep/mask-seed ride-alongs ---
    hipLaunchKernelGGL(k_part, dim3(NPP + PREP_BLKS + MB_BLKS), dim3(1024), 0, stream,
                       src, dst, ew, gCursor, tmp, mask, maskbit, needed, W1, Wt1);

    // --- per-bucket dis (LDS accumulation over tmp slots) fused with GEMM1 ---
    hipLaunchKernelGGL(k_disA_g1, dim3(NB + MF_BLKS), dim3(256), 0, stream,
                       tmp, gCursor, dis, x, Wt1, A);

    // --- fused sort + layer-1 aggregate: B = relu(agg(A) + b1); pairs for masked dsts ---
    hipLaunchKernelGGL(k_sort_agg, dim3(NB), dim3(1024), 0, stream,
                       tmp, gCursor, dis, needed, maskbit, b1,
                       (const unsigned int*)A, rowStart, rowLen, pairs, (unsigned int*)B);

    // --- fused layer-2 at mask nodes: out = agg(B)@W2 + b2 (+ labels) ---
    hipLaunchKernelGGL(k_mask_out, dim3(M / 4), dim3(256), 0, stream,
                       (const unsigned int*)B, pairs, rowStart, rowLen, dis, W2, b2,
                       mask, y, (float*)d_out);
}

// Round 14
// 236.105 us; speedup vs baseline: 1.0855x; 1.0054x over previous
//
#include <hip/hip_runtime.h>

// Problem constants (fixed by the reference).
constexpr int N = 100000;   // nodes
constexpr int E = 1600000;  // edges
constexpr int D = 128;      // feature dim (both layers)
constexpr int M = 5000;     // mask size

constexpr int MF_BLKS = (N + 255) / 256;           // 391 mfma-gemm blocks (256 rows each)

// Counting-sort CSR build parameters.
// Bucket = dst>>7 (128 nodes) -> 782 buckets, each with a FIXED 3072-record slot in
// tmp/pairs: counts are Binomial(1.6M, 1/782) = 2046 +/- 45, CAP is +22 sigma.
// No histogram, no scan; cursors are RELATIVE (start 0, zeroed by the memset).
// R8: per-dst global float atomics cost ~70us (never again).
// R10: gather tiers beyond 8-deep add VALU cost, no win.
// R11: needed-scan must stay in k_part (high TLP); maskbit dep removed via
// block-local LDS bitmap (R13) -> no misc0 kernel.
// R13 lesson: k_sort_agg at 1024 thr REGRESSED (53.2 vs 50.2) despite higher
// occupancy% -- at 512 thr all 782 blocks are co-resident (4/CU cap) and the CU
// scheduler balances buckets naturally; 1024 thr forces a 270-block tail round.
constexpr int NBITS = 7;
constexpr int BUCKET = 1 << NBITS;                 // 128 nodes per bucket
constexpr int NB  = (N + BUCKET - 1) / BUCKET;     // 782 buckets
constexpr int CAP = 3072;                          // records per bucket slot (= 512*6)
constexpr int EBP = 4096;                          // edges per partition block
constexpr int NPP = (E + EBP - 1) / EBP;           // 391 partition blocks (1024 thr each)
constexpr int PREP_BLKS = 8;                       // W1-prep ride-along blocks (1024 thr)
constexpr int MB_BLKS = (M + 1023) / 1024;         // 5 mask-seed ride-along blocks
constexpr int MBW = 4096;                          // LDS maskbit words (131072 bits >= N)

typedef __attribute__((ext_vector_type(8))) short bf16x8;
typedef __attribute__((ext_vector_type(4))) float f32x4;

// ---------------- bf16 helpers (RNE pack, cheap unpack) ----------------

__device__ __forceinline__ unsigned int pack_bf16x2(float a, float b) {
    unsigned int ua = __float_as_uint(a);
    unsigned int ub = __float_as_uint(b);
    ua = (ua + 0x7FFFu + ((ua >> 16) & 1u)) >> 16;
    ub = (ub + 0x7FFFu + ((ub >> 16) & 1u)) & 0xFFFF0000u;
    return ua | ub;
}
__device__ __forceinline__ unsigned short bf16_rne(float a) {
    unsigned int ua = __float_as_uint(a);
    return (unsigned short)((ua + 0x7FFFu + ((ua >> 16) & 1u)) >> 16);
}
__device__ __forceinline__ float bf16_lo(unsigned int u) { return __uint_as_float(u << 16); }
__device__ __forceinline__ float bf16_hi(unsigned int u) { return __uint_as_float(u & 0xFFFF0000u); }

// ---------------- partition (+ W1-prep, mask-seed ride-alongs) ----------------
// record: bits[6:0]=d&127, bits[26:7]=src, bits[63:32]=ew bits.
// Cursors bucket-relative (zeroed by memset); pos = b*CAP + off+r.
// needed-scan uses a BLOCK-LOCAL LDS maskbit built from mask[] (5000 ints, L2
// broadcast) -- no dependency on the global bitmap, so no preceding kernel.
// Global maskbit/needed seeds ride along (consumed by k_sort_agg, 2 launches later).

__global__ __launch_bounds__(1024) void k_part(const int* __restrict__ src,
                                               const int* __restrict__ dst,
                                               const float* __restrict__ ew,
                                               int* __restrict__ gCursor,
                                               unsigned long long* __restrict__ tmp,
                                               const int* __restrict__ mask,
                                               unsigned int* __restrict__ maskbit,
                                               unsigned int* __restrict__ needed,
                                               const float* __restrict__ W1,
                                               unsigned int* __restrict__ Wt1) {
    __shared__ int cnt[NB];
    __shared__ int off[NB];
    __shared__ int rk[NB];
    __shared__ unsigned int mbit[MBW];
    const int t = threadIdx.x;

    if (blockIdx.x >= NPP) {
        const int bi = blockIdx.x - NPP;
        if (bi < PREP_BLKS) {
            int idx = bi * 1024 + t;   // 8192 total (W1 only; W2 used in fp32)
            if (idx < 8192) {
                int n = idx >> 6, kk = idx & 63;
                float a = W1[(2 * kk) * D + n];
                float b = W1[(2 * kk + 1) * D + n];
                Wt1[idx] = pack_bf16x2(a, b);
            }
        } else {
            int i = (bi - PREP_BLKS) * 1024 + t;
            if (i < M) {
                int n = mask[i];
                atomicOr(&maskbit[n >> 5], 1u << (n & 31));
                atomicOr(&needed[n >> 5], 1u << (n & 31));  // masked nodes need their row
            }
        }
        return;
    }

    for (int i = t; i < NB; i += 1024) { cnt[i] = 0; rk[i] = 0; }
    for (int i = t; i < MBW; i += 1024) mbit[i] = 0;
    __syncthreads();

    // build block-local maskbit (overlaps with the record loads below)
    for (int i = t; i < M; i += 1024) {
        int n = mask[i];
        atomicOr(&mbit[n >> 5], 1u << (n & 31));
    }

    const int eb = blockIdx.x * EBP;
    int d_[4], s_[4];
    float w_[4];
#pragma unroll
    for (int i = 0; i < 4; ++i) {
        int e = eb + t + i * 1024;
        if (e < E) {
            d_[i] = __builtin_nontemporal_load(dst + e);
            s_[i] = __builtin_nontemporal_load(src + e);
            w_[i] = __builtin_nontemporal_load(ew + e);
            atomicAdd(&cnt[d_[i] >> NBITS], 1);
        } else {
            d_[i] = -1;
        }
    }
    __syncthreads();

    for (int i = t; i < NB; i += 1024) {
        int c = cnt[i];
        if (c > 0) off[i] = atomicAdd(&gCursor[i], c);   // relative reservation
    }
    __syncthreads();

#pragma unroll
    for (int i = 0; i < 4; ++i) {
        if (d_[i] >= 0) {
            int b = d_[i] >> NBITS;
            int r = atomicAdd(&rk[b], 1);
            int posr = off[b] + r;
            if (posr < CAP) {   // overflow guard (+22 sigma; never expected)
                unsigned long long rec =
                    ((unsigned long long)(unsigned int)__float_as_int(w_[i]) << 32) |
                    ((unsigned int)s_[i] << NBITS) | (unsigned int)(d_[i] & (BUCKET - 1));
                tmp[(size_t)b * CAP + posr] = rec;   // cached: L2 merges the ~42B runs
            }
            if ((mbit[d_[i] >> 5] >> (d_[i] & 31)) & 1u)
                atomicOr(&needed[s_[i] >> 5], 1u << (s_[i] & 31));
        }
    }
}

// ---------------- shared-memory union: GEMM W-tile OR dis-accumulation array ----------------

union SMem {
    unsigned int Ws[128 * 68];
    float wsumL[BUCKET];
};

// ---------------- MFMA GEMM body: 256 rows/block, 4 waves; wave = 64 rows x 128 cols ----------------
// A-frag: A[m=lane&15][k=quad*8+j]; B-frag: B[k=quad*8+j][n=lane&15];
// D: col=lane&15, row=quad*4+reg  (HW-verified layouts, 16x16x32 bf16).
// W^T staged in LDS with 68-uint row stride (bank-conflict padding).

__device__ __forceinline__ void gemm_mfma_body(unsigned int* __restrict__ Ws,
                                               const float* __restrict__ Xin,
                                               const unsigned int* __restrict__ Wt,
                                               unsigned short* __restrict__ out, int blk) {
    const int t = threadIdx.x;
#pragma unroll
    for (int i = 0; i < 8; ++i) {
        int f4 = t + i * 256;        // uint4 index, 2048 total
        int n = f4 >> 4;
        int k4 = f4 & 15;
        uint4 w = ((const uint4*)Wt)[f4];
        *(uint4*)(&Ws[n * 68 + k4 * 4]) = w;
    }
    __syncthreads();

    const int wv = t >> 6, lane = t & 63;
    const int q = lane >> 4, l15 = lane & 15;
    const int rowBase = blk * 256 + wv * 64;

    f32x4 acc[4][8] = {};
#pragma unroll
    for (int kc = 0; kc < 4; ++kc) {
        bf16x8 af[4];
#pragma unroll
        for (int rt = 0; rt < 4; ++rt) {
            int row = rowBase + rt * 16 + l15;
            if (row > N - 1) row = N - 1;   // tail: duplicate last row, stores guarded
            union { uint4 u; bf16x8 v; } cv;
            const float* xr = Xin + (size_t)row * D + kc * 32 + q * 8;
            float4 x0 = *(const float4*)xr;
            float4 x1 = *(const float4*)(xr + 4);
            cv.u.x = pack_bf16x2(x0.x, x0.y);
            cv.u.y = pack_bf16x2(x0.z, x0.w);
            cv.u.z = pack_bf16x2(x1.x, x1.y);
            cv.u.w = pack_bf16x2(x1.z, x1.w);
            af[rt] = cv.v;
        }
#pragma unroll
        for (int ct = 0; ct < 8; ++ct) {
            union { uint4 u; bf16x8 v; } bv;
            bv.u = *(const uint4*)(&Ws[(ct * 16 + l15) * 68 + kc * 16 + q * 4]);
#pragma unroll
            for (int rt = 0; rt < 4; ++rt)
                acc[rt][ct] = __builtin_amdgcn_mfma_f32_16x16x32_bf16(af[rt], bv.v, acc[rt][ct], 0, 0, 0);
        }
    }

#pragma unroll
    for (int rt = 0; rt < 4; ++rt) {
#pragma unroll
        for (int ct = 0; ct < 8; ++ct) {
            int col = ct * 16 + l15;
#pragma unroll
            for (int r = 0; r < 4; ++r) {
                int row = rowBase + rt * 16 + q * 4 + r;
                if (row < N) out[(size_t)row * D + col] = bf16_rne(acc[rt][ct][r]);
            }
        }
    }
}

// ---------------- fused: per-bucket dis (blocks 0..NB) + GEMM1 (blocks NB..) ----------------
// dis blocks stream their bucket's tmp slot once (sequential, mostly L2-warm),
// accumulate weighted in-degree in LDS, write dis = rsqrt(1+wsum).

__global__ __launch_bounds__(256) void k_disA_g1(const unsigned long long* __restrict__ tmp,
                                                 const int* __restrict__ gCursor,
                                                 float* __restrict__ dis,
                                                 const float* __restrict__ x,
                                                 const unsigned int* __restrict__ Wt1,
                                                 unsigned short* __restrict__ A) {
    __shared__ SMem sm;
    const int t = threadIdx.x;
    if (blockIdx.x < NB) {
        const int bk = blockIdx.x;
        if (t < BUCKET) sm.wsumL[t] = 0.f;
        __syncthreads();
        const size_t segBeg = (size_t)bk * CAP;
        int segLen = gCursor[bk];
        if (segLen > CAP) segLen = CAP;
        for (int e = t; e < segLen; e += 256) {
            unsigned long long rec = tmp[segBeg + e];
            atomicAdd(&sm.wsumL[(int)(rec & (BUCKET - 1))],
                      __uint_as_float((unsigned int)(rec >> 32)));
        }
        __syncthreads();
        if (t < BUCKET) {
            int node = bk * BUCKET + t;
            if (node < N) dis[node] = rsqrtf(1.0f + sm.wsumL[t]);
        }
    } else {
        gemm_mfma_body(sm.Ws, x, Wt1, A, blockIdx.x - NB);
    }
}

// ---------------- fused sort+aggregate: block (512 thr, 8 waves) per bucket ----------------
// 512 threads: all 782 blocks co-resident (4-block/CU cap) -> natural cross-bucket
// balance (R13: 1024 thr regressed via a 270-block tail round).
// Records in REGISTERS (<=6/thread since CAP = 512*6): phase0 counts via LDS atomics;
// prefix -> offL, rowStart/rowLen, needed worklist; phase1 scatters (src, ew*dis[src])
// into LDS (global pairs only for masked dsts); phase2: waves pop needed nodes
// (8-deep + scalar body, R9-proven).

__global__ __launch_bounds__(512) void k_sort_agg(const unsigned long long* __restrict__ tmp,
                                                  const int* __restrict__ gCursor,
                                                  const float* __restrict__ dis,
                                                  const unsigned int* __restrict__ needed,
                                                  const unsigned int* __restrict__ maskbit,
                                                  const float* __restrict__ b,
                                                  const unsigned int* __restrict__ Hb,
                                                  int* __restrict__ rowStart,
                                                  int* __restrict__ rowLen,
                                                  int2* __restrict__ pairs,
                                                  unsigned int* __restrict__ outB) {
    __shared__ int2 lp[CAP];
    __shared__ int cnt[BUCKET];
    __shared__ int offL[BUCKET + 1];
    __shared__ int wl[BUCKET];
    __shared__ int waveS[2];
    __shared__ int nw, wcur;
    const int bk = blockIdx.x;
    const int t = threadIdx.x;
    const size_t segBeg = (size_t)bk * CAP;
    int segLen = gCursor[bk];
    if (segLen > CAP) segLen = CAP;   // matches k_part's overflow guard

    if (t == 0) { nw = 0; wcur = 0; offL[BUCKET] = segLen; }
    if (t < BUCKET) cnt[t] = 0;
    const uint4 mb4 = ((const uint4*)maskbit)[bk];   // this bucket's 128 mask bits
    __syncthreads();

    // phase 0: load records into registers, count per local-dst
    unsigned long long r_[6];
#pragma unroll
    for (int i = 0; i < 6; ++i) {
        int e = t + i * 512;
        if (e < segLen) {
            r_[i] = tmp[segBeg + e];
            atomicAdd(&cnt[(int)(r_[i] & (BUCKET - 1))], 1);
        }
    }
    __syncthreads();

    // prefix over cnt (threads 0..127), rowStart/rowLen, worklist build
    const int lane = t & 63;
    {
        const int wv2 = t >> 6;
        const int pv = (t < BUCKET) ? cnt[t] : 0;
        int v = pv;
        for (int o = 1; o < 64; o <<= 1) {
            int u = __shfl_up(v, o);
            if (lane >= o) v += u;
        }
        if (lane == 63 && wv2 < 2) waveS[wv2] = v;
        __syncthreads();
        if (t < BUCKET) {
            const int wb = (wv2 == 1) ? waveS[0] : 0;
            const int ex = wb + v - pv;
            offL[t] = ex;
            const int node = bk * BUCKET + t;
            if (node < N) {
                rowStart[node] = (int)segBeg + ex;
                rowLen[node] = pv;
                if ((needed[node >> 5] >> (node & 31)) & 1u) {
                    int r = atomicAdd(&nw, 1);
                    wl[r] = t;
                }
            }
            cnt[t] = 0;
        }
    }
    __syncthreads();

    // phase 1: scatter registers -> LDS (prescaled); global pairs only for masked dsts
#pragma unroll
    for (int i = 0; i < 6; ++i) {
        int e = t + i * 512;
        if (e < segLen) {
            unsigned long long rec = r_[i];
            int dl = (int)(rec & (BUCKET - 1));
            int s  = (int)((rec >> NBITS) & 0xFFFFF);
            float w = __uint_as_float((unsigned int)(rec >> 32));
            float v = w * dis[s];             // per-thread gather, 64 edges/instr
            int r = atomicAdd(&cnt[dl], 1);
            int pos = offL[dl] + r;
            int2 pr = make_int2(s, __float_as_int(v));
            lp[pos] = pr;
            unsigned int mw = (dl < 32) ? mb4.x : (dl < 64) ? mb4.y : (dl < 96) ? mb4.z : mb4.w;
            if ((mw >> (dl & 31)) & 1u) pairs[segBeg + pos] = pr;
        }
    }
    __syncthreads();

    // phase 2: waves pop needed nodes from the worklist
    for (;;) {
        int idx;
        if (lane == 0) idx = atomicAdd(&wcur, 1);
        idx = __shfl(idx, 0);
        if (idx >= nw) break;
        const int nl = wl[idx];
        const int node = bk * BUCKET + nl;
        const int beg = offL[nl], end = offL[nl + 1];
        float ax = 0.f, ay = 0.f;
        int j = beg;
        for (; j + 7 < end; j += 8) {
            int2 p[8];
            unsigned int h[8];
#pragma unroll
            for (int i = 0; i < 8; ++i) p[i] = lp[j + i];
#pragma unroll
            for (int i = 0; i < 8; ++i) h[i] = Hb[(size_t)p[i].x * 64 + lane];
#pragma unroll
            for (int i = 0; i < 8; ++i) {
                float v = __int_as_float(p[i].y);
                ax += bf16_lo(h[i]) * v;
                ay += bf16_hi(h[i]) * v;
            }
        }
        for (; j < end; ++j) {
            int2 p0 = lp[j];
            unsigned int h0 = Hb[(size_t)p0.x * 64 + lane];
            float v0 = __int_as_float(p0.y);
            ax += bf16_lo(h0) * v0;
            ay += bf16_hi(h0) * v0;
        }
        float dd = dis[node];
        float sn = dd * dd;  // self-loop norm = 1/deg
        unsigned int hs = Hb[(size_t)node * 64 + lane];
        float2 bb = ((const float2*)b)[lane];
        float ox = fmaxf(ax * dd + bf16_lo(hs) * sn + bb.x, 0.f);
        float oy = fmaxf(ay * dd + bf16_hi(hs) * sn + bb.y, 0.f);
        __builtin_nontemporal_store(pack_bf16x2(ox, oy), outB + (size_t)node * 64 + lane);
    }
}

// ---------------- fused layer-2 at mask nodes: out = agg(B)@W2 + b2 ----------------
// (agg is linear, so agg(B@W2) = agg(B)@W2.) Wave per mask row: gather-aggregate B,
// park the row in LDS, then multiply by W2 staged in LDS (two 64-row halves).

__global__ __launch_bounds__(256) void k_mask_out(const unsigned int* __restrict__ Hb,
                                                  const int2* __restrict__ pairs,
                                                  const int* __restrict__ rowStart,
                                                  const int* __restrict__ rowLen,
                                                  const float* __restrict__ dis,
                                                  const float* __restrict__ W2,
                                                  const float* __restrict__ b2,
                                                  const int* __restrict__ mask,
                                                  const int* __restrict__ y,
                                                  float* __restrict__ out) {
    __shared__ float w2s[64 * 132];   // 132 stride: float4-aligned stores, bank spread
    __shared__ float rowL[4][128];
    const int t = threadIdx.x;
    const int wv = t >> 6, lane = t & 63;
    const int i = blockIdx.x * 4 + wv;   // grid = M/4 exactly (1250*4 = 5000)
    const int node = mask[i];
    const int beg = rowStart[node], end = beg + rowLen[node];

    float ax = 0.f, ay = 0.f;
    int j = beg;
    for (; j + 7 < end; j += 8) {
        int2 p[8];
        unsigned int h[8];
#pragma unroll
        for (int ii = 0; ii < 8; ++ii) p[ii] = pairs[j + ii];
#pragma unroll
        for (int ii = 0; ii < 8; ++ii) h[ii] = Hb[(size_t)p[ii].x * 64 + lane];
#pragma unroll
        for (int ii = 0; ii < 8; ++ii) {
            float v = __int_as_float(p[ii].y);
            ax += bf16_lo(h[ii]) * v;
            ay += bf16_hi(h[ii]) * v;
        }
    }
    for (; j < end; ++j) {
        int2 p0 = pairs[j];
        unsigned int h0 = Hb[(size_t)p0.x * 64 + lane];
        float v0 = __int_as_float(p0.y);
        ax += bf16_lo(h0) * v0;
        ay += bf16_hi(h0) * v0;
    }
    {
        float dd = dis[node];
        float sn = dd * dd;
        unsigned int hs = Hb[(size_t)node * 64 + lane];
        rowL[wv][2 * lane]     = ax * dd + bf16_lo(hs) * sn;   // bias b2 added post-GEMM
        rowL[wv][2 * lane + 1] = ay * dd + bf16_hi(hs) * sn;
    }

    float2 bb = ((const float2*)b2)[lane];
    float acc0 = bb.x, acc1 = bb.y;
#pragma unroll
    for (int h0 = 0; h0 < 2; ++h0) {
        __syncthreads();
        for (int idx = t; idx < 2048; idx += 256) {   // stage 64 rows of W2 (float4 units)
            float4 v = ((const float4*)W2)[h0 * 2048 + idx];
            int k = (idx * 4) >> 7, n = (idx * 4) & 127;
            *(float4*)(&w2s[k * 132 + n]) = v;
        }
        __syncthreads();
#pragma unroll 8
        for (int k = 0; k < 64; ++k) {
            float a = rowL[wv][h0 * 64 + k];
            float2 w = *(const float2*)(&w2s[k * 132 + 2 * lane]);
            acc0 += a * w.x;
            acc1 += a * w.y;
        }
    }
    ((float2*)(out + (size_t)i * D))[lane] = make_float2(acc0, acc1);
    if (lane == 0) out[(size_t)M * D + i] = (float)y[node];
}

extern "C" void kernel_launch(void* const* d_in, const int* in_sizes, int n_in,
                              void* d_out, int out_size, void* d_ws, size_t ws_size,
                              hipStream_t stream) {
    const float* x  = (const float*)d_in[0];
    const float* ew = (const float*)d_in[1];
    const float* W1 = (const float*)d_in[2];
    const float* b1 = (const float*)d_in[3];
    const float* W2 = (const float*)d_in[4];
    const float* b2 = (const float*)d_in[5];
    const int* eidx = (const int*)d_in[6];
    const int* mask = (const int*)d_in[7];
    const int* y    = (const int*)d_in[8];
    const int* src = eidx;       // edge_index[0]
    const int* dst = eidx + E;   // edge_index[1]

    // Workspace layout (bytes):
    //   dis       @ 0        : N f32        (0.4 MB)
    //   rowStart  @ 512 KB   : N i32        (0.4 MB)
    //   rowLen    @ 1024 KB  : N i32        (0.4 MB)
    //   maskbit   @ 1440 KB  : 16 KB bitmap }
    //   needed    @ 1456 KB  : 16 KB bitmap }  zeroed together (36 KB memset,
    //   gCursor   @ 1472 KB  : NB i32       }   covers relative cursors too)
    //   Wt1       @ 1480 KB  : 8192 u32    (32 KB)
    //   pairs     @ 2 MB     : NB*CAP int2 (19.2 MB, sparsely written)
    //   tmp       @ 22 MB    : NB*CAP u64  (19.2 MB)
    //   A  (bf16) @ 42 MB    : N*D bf16    (25.6 MB)
    //   B  (bf16) @ 68 MB    : N*D bf16    (25.6 MB)   total ~94 MB
    char* ws = (char*)d_ws;
    float* dis      = (float*)(ws);
    int*   rowStart = (int*)(ws + (size_t)512 * 1024);
    int*   rowLen   = (int*)(ws + (size_t)1024 * 1024);
    unsigned int* maskbit = (unsigned int*)(ws + (size_t)1440 * 1024);
    unsigned int* needed  = (unsigned int*)(ws + (size_t)1456 * 1024);
    int*   gCursor  = (int*)(ws + (size_t)1472 * 1024);
    unsigned int* Wt1 = (unsigned int*)(ws + (size_t)1480 * 1024);
    int2*  pairs    = (int2*)(ws + (size_t)2 * 1024 * 1024);
    unsigned long long* tmp = (unsigned long long*)(ws + (size_t)22 * 1024 * 1024);
    unsigned short* A  = (unsigned short*)(ws + (size_t)42 * 1024 * 1024);
    unsigned short* B  = (unsigned short*)(ws + (size_t)68 * 1024 * 1024);

    // --- zero bitmaps + relative cursors ---
    (void)hipMemsetAsync(ws + (size_t)1440 * 1024, 0, (size_t)36 * 1024, stream);

    // --- partition + needed-scan (LDS-local maskbit) + W1-prep/mask-seed ride-alongs ---
    hipLaunchKernelGGL(k_part, dim3(NPP + PREP_BLKS + MB_BLKS), dim3(1024), 0, stream,
                       src, dst, ew, gCursor, tmp, mask, maskbit, needed, W1, Wt1);

    // --- per-bucket dis (LDS accumulation over tmp slots) fused with GEMM1 ---
    hipLaunchKernelGGL(k_disA_g1, dim3(NB + MF_BLKS), dim3(256), 0, stream,
                       tmp, gCursor, dis, x, Wt1, A);

    // --- fused sort + layer-1 aggregate: B = relu(agg(A) + b1); pairs for masked dsts ---
    hipLaunchKernelGGL(k_sort_agg, dim3(NB), dim3(512), 0, stream,
                       tmp, gCursor, dis, needed, maskbit, b1,
                       (const unsigned int*)A, rowStart, rowLen, pairs, (unsigned int*)B);

    // --- fused layer-2 at mask nodes: out = agg(B)@W2 + b2 (+ labels) ---
    hipLaunchKernelGGL(k_mask_out, dim3(M / 4), dim3(256), 0, stream,
                       (const unsigned int*)B, pairs, rowStart, rowLen, dis, W2, b2,
                       mask, y, (float*)d_out);
}